// Round 15
// baseline (437.406 us; speedup 1.0000x reference)
//
#include <hip/hip_runtime.h>

// GCNEncoder round 15: round-12/14 pipeline with FINER CSR buckets
// (128 nodes/bucket, NBKT 196->391): halves the serial record work of each
// P3 bucket block (the ~40us long pole: only 196 blocks carried the 2-pass
// LDS-atomic record loops while 1563 gemm1 blocks finished early).
constexpr int N_NODES  = 50000;
constexpr int N_EDGES  = 800000;
constexpr int N_GRAPHS = 256;
constexpr int IN_DIM   = 128;
constexpr int HID      = 64;
constexpr int EMB      = 128;
constexpr int NBKT     = 391;                       // buckets: dst>>7 (128 nodes)
constexpr int EB       = (N_EDGES + 1023) / 1024;   // 782 edge blocks
constexpr int GB       = (N_NODES + 31) / 32;       // 1563 gemm1 blocks (32 nodes)
constexpr int GSB      = (N_NODES + 255) / 256;     // 196 gstart blocks
constexpr int NB2      = 64;                        // nodes per gemm2_pool block

// Workspace layout in 4-byte units (~33.8 MB; ws is 268 MB).
constexpr size_t OFF_POOL  = 0;                                 // f32 [256*128]
constexpr size_t OFF_GST   = 32768;                             // i32 [257]
constexpr size_t OFF_BBASE = 33026;                             // i32 [392]
constexpr size_t OFF_DIS   = 33420;                             // f32 [50000]
constexpr size_t OFF_RS    = 83420;                             // i32 [50000]
constexpr size_t OFF_HCNT  = 133420;                            // i32 [782*391]
constexpr size_t OFF_REC   = 439184;                            // uint2 [800000] (8B-aligned)
constexpr size_t OFF_PART  = OFF_REC + 2 * (size_t)N_EDGES;     // uint4 [800000] (16B-aligned)
constexpr size_t OFF_H1    = OFF_PART;  // bf16x2 [50000*32]; overlays part (dead after P3)
constexpr size_t OFF_H1P   = OFF_PART + 4 * (size_t)N_EDGES;    // bf16x2 [50000*32]
constexpr size_t OFF_AGG2  = OFF_H1P;   // f32 [50000*64]; overlays h1p (dead after gather1)

// bf16 helpers: pack with round-to-nearest-even; unpack via shift.
__device__ inline unsigned bf16r(float f) {
    unsigned u = __float_as_uint(f);
    return (u + 0x7fffu + ((u >> 16) & 1u)) >> 16;
}
__device__ inline unsigned bf16pack2(float lo, float hi) {
    return bf16r(lo) | (bf16r(hi) << 16);
}
__device__ inline float bflo(unsigned v) { return __uint_as_float(v << 16); }
__device__ inline float bfhi(unsigned v) { return __uint_as_float(v & 0xffff0000u); }

__device__ inline void fma4(float4& acc, float s, const float4& v) {
    acc.x += s * v.x; acc.y += s * v.y; acc.z += s * v.z; acc.w += s * v.w;
}

// ---- P1: per-block bucket histogram (LDS atomics only) ----
__global__ __launch_bounds__(256) void k_p1(const int* __restrict__ dst,
                                            int* __restrict__ hcnt) {
    __shared__ int lh[NBKT];
    int tid = threadIdx.x;
    for (int i = tid; i < NBKT; i += 256) lh[i] = 0;
    __syncthreads();
    int base = blockIdx.x * 1024;
    #pragma unroll
    for (int j = 0; j < 4; ++j) {
        int e = base + j * 256 + tid;
        if (e < N_EDGES) atomicAdd(&lh[dst[e] >> 7], 1);
    }
    __syncthreads();
    for (int i = tid; i < NBKT; i += 256) hcnt[blockIdx.x * NBKT + i] = lh[i];
}

// ---- KAB: bucket totals + exclusive scan -> bbase[NBKT+1] (one block) ----
// 391 buckets: two 256-entry tiles, scan each, splice with first-half total.
__global__ __launch_bounds__(256) void k_kab(const int* __restrict__ hcnt,
                                             int* __restrict__ bbase) {
    __shared__ int tile[512];
    int t = threadIdx.x;
    int v0 = 0, v1 = 0;
    for (int i = 0; i < EB; ++i) {
        v0 += hcnt[i * NBKT + t];
        if (t + 256 < NBKT) v1 += hcnt[i * NBKT + t + 256];
    }
    tile[t] = v0;
    tile[256 + t] = (t + 256 < NBKT) ? v1 : 0;
    __syncthreads();
    for (int off = 1; off < 256; off <<= 1) {
        int a0 = (t >= off) ? tile[t - off] : 0;
        int a1 = (t >= off) ? tile[256 + t - off] : 0;
        __syncthreads();
        tile[t] += a0;
        tile[256 + t] += a1;
        __syncthreads();
    }
    int h0 = tile[255];                       // first-half inclusive total
    tile[256 + t] += h0;                      // each thread touches only its own entry
    bbase[t] = tile[t] - v0;                  // exclusive
    if (t + 256 < NBKT) bbase[256 + t] = tile[256 + t] - v1;
    if (t + 256 == NBKT - 1) bbase[NBKT] = tile[256 + t];   // total = N_EDGES
}

// ---- KC: per-bucket column scan of hcnt in place (+ gstart role) ----
__global__ __launch_bounds__(256) void k_kc(int* __restrict__ hcnt,
                                            const int* __restrict__ bbase,
                                            const int* __restrict__ batch,
                                            int* __restrict__ gstart) {
    __shared__ int tile[256];
    __shared__ int carry;
    int t = threadIdx.x;
    if (blockIdx.x < NBKT) {
        int b = blockIdx.x;
        if (t == 0) carry = bbase[b];
        __syncthreads();
        for (int i0 = 0; i0 < EB; i0 += 256) {
            int i = i0 + t;
            int v = (i < EB) ? hcnt[i * NBKT + b] : 0;
            tile[t] = v;
            __syncthreads();
            for (int off = 1; off < 256; off <<= 1) {
                int a = (t >= off) ? tile[t - off] : 0;
                __syncthreads();
                tile[t] += a;
                __syncthreads();
            }
            int incl = tile[t];
            if (i < EB) hcnt[i * NBKT + b] = carry + incl - v;   // exclusive + carry
            __syncthreads();
            if (t == 255) carry += incl;
            __syncthreads();
        }
        return;
    }
    // ---- gstart role: sorted-batch boundary detection ----
    int i = (blockIdx.x - NBKT) * 256 + t;
    if (i >= N_NODES) return;
    int g = batch[i];
    if (i == 0) {
        for (int gg = 0; gg <= g; ++gg) gstart[gg] = 0;
    } else {
        int gp = batch[i - 1];
        for (int gg = gp + 1; gg <= g; ++gg) gstart[gg] = i;
    }
    if (i == N_NODES - 1) {
        for (int gg = g + 1; gg <= N_GRAPHS; ++gg) gstart[gg] = N_NODES;
    }
}

// ---- P2: partition edges into buckets (LDS cursors, no global atomics) ----
__global__ __launch_bounds__(256) void k_p2(const int* __restrict__ src,
                                            const int* __restrict__ dst,
                                            const float* __restrict__ ew,
                                            const int* __restrict__ hcnt,
                                            uint4* __restrict__ part) {
    __shared__ int lb[NBKT];
    __shared__ int lc[NBKT];
    int tid = threadIdx.x;
    for (int i = tid; i < NBKT; i += 256) {
        lb[i] = hcnt[blockIdx.x * NBKT + i];
        lc[i] = 0;
    }
    __syncthreads();
    int base = blockIdx.x * 1024;
    #pragma unroll
    for (int j = 0; j < 4; ++j) {
        int e = base + j * 256 + tid;
        if (e < N_EDGES) {
            int d = dst[e];
            int b = d >> 7;
            int r = atomicAdd(&lc[b], 1);
            part[lb[b] + r] = make_uint4((unsigned)src[e], (unsigned)d,
                                         __float_as_uint(ew[e]), 0u);
        }
    }
}

// ---- P3 (+gemm1 het-fused): per-bucket CSR finalize + degree + dis ----
// blocks [0,NBKT): bucket b = 128 contiguous nodes; ~2040 records/block.
// blocks [NBKT,NBKT+GB): h1p(bf16) = x @ W1 (32 nodes/block).
__global__ __launch_bounds__(256) void k_p3_gemm1(const uint4* __restrict__ part,
                                                  const int* __restrict__ bbase,
                                                  int* __restrict__ rs,
                                                  float* __restrict__ dis,
                                                  uint2* __restrict__ rec,
                                                  const float* __restrict__ x,
                                                  const float* __restrict__ W1,
                                                  unsigned* __restrict__ h) {
    __shared__ float Ws[IN_DIM * HID];      // 32 KB (gemm role)
    __shared__ float xs[32][IN_DIM + 4];    // 16.5 KB, stride 132 -> conflict-free
    __shared__ int   cnt[128];
    __shared__ float dgw[128];
    __shared__ int   scn[128];
    __shared__ int   cur[128];
    int tid = threadIdx.x;
    if (blockIdx.x < NBKT) {
        int b = blockIdx.x;
        int base_node = b << 7;
        int ebeg = bbase[b], eend = bbase[b + 1];
        if (tid < 128) { cnt[tid] = 0; dgw[tid] = 0.f; }
        __syncthreads();
        for (int e = ebeg + tid; e < eend; e += 256) {
            uint4 r = part[e];
            int ld = (int)r.y & 127;
            atomicAdd(&cnt[ld], 1);
            atomicAdd(&dgw[ld], __uint_as_float(r.z));
        }
        __syncthreads();
        if (tid < 128) scn[tid] = cnt[tid];
        __syncthreads();
        for (int off = 1; off < 128; off <<= 1) {
            int a = (tid >= off && tid < 128) ? scn[tid - off] : 0;
            __syncthreads();
            if (tid < 128) scn[tid] += a;
            __syncthreads();
        }
        if (tid < 128) {
            int node = base_node + tid;
            if (node < N_NODES) {
                rs[node] = ebeg + scn[tid];             // end pointer
                dis[node] = rsqrtf(dgw[tid] + 1.0f);    // + self-loop weight 1
            }
            cur[tid] = ebeg + scn[tid] - cnt[tid];      // row start cursor
        }
        __syncthreads();
        for (int e = ebeg + tid; e < eend; e += 256) {
            uint4 r = part[e];
            int ld = (int)r.y & 127;
            int pos = atomicAdd(&cur[ld], 1);
            rec[pos] = make_uint2(r.x, r.z);            // (src, ew_bits)
        }
        return;
    }
    // ---- gemm1 role: 32 nodes/block, thread = 2 nodes x 4 cols ----
    int bid = blockIdx.x - NBKT;
    const float4* W4 = (const float4*)W1;
    float4* Ws4 = (float4*)Ws;
    for (int i = tid; i < IN_DIM * HID / 4; i += 256) Ws4[i] = W4[i];
    int base = bid * 32;
    const float4* X4 = (const float4*)x;
    for (int i = tid; i < 32 * 32; i += 256) {           // 32 rows x 32 float4
        int ln = i >> 5, kq = i & 31;
        int node = base + ln;
        float4 v = (node < N_NODES) ? X4[(size_t)node * 32 + kq]
                                    : make_float4(0.f, 0.f, 0.f, 0.f);
        *(float4*)&xs[ln][kq * 4] = v;
    }
    __syncthreads();
    int np = tid >> 4;            // node pair 0..15
    int q  = tid & 15;            // col quad 0..15
    int n0 = np * 2, n1 = n0 + 1;
    float4 a0 = make_float4(0.f, 0.f, 0.f, 0.f);
    float4 a1 = a0;
    #pragma unroll 4
    for (int k4 = 0; k4 < IN_DIM; k4 += 4) {
        float4 xv0 = *(const float4*)&xs[n0][k4];
        float4 xv1 = *(const float4*)&xs[n1][k4];
        float4 w0 = Ws4[(k4 + 0) * 16 + q];
        float4 w1 = Ws4[(k4 + 1) * 16 + q];
        float4 w2 = Ws4[(k4 + 2) * 16 + q];
        float4 w3 = Ws4[(k4 + 3) * 16 + q];
        fma4(a0, xv0.x, w0); fma4(a0, xv0.y, w1); fma4(a0, xv0.z, w2); fma4(a0, xv0.w, w3);
        fma4(a1, xv1.x, w0); fma4(a1, xv1.y, w1); fma4(a1, xv1.z, w2); fma4(a1, xv1.w, w3);
    }
    int nd0 = base + n0, nd1 = base + n1;
    if (nd0 < N_NODES) {
        uint2 p = make_uint2(bf16pack2(a0.x, a0.y), bf16pack2(a0.z, a0.w));
        ((uint2*)h)[(size_t)nd0 * 16 + q] = p;
    }
    if (nd1 < N_NODES) {
        uint2 p = make_uint2(bf16pack2(a1.x, a1.y), bf16pack2(a1.z, a1.w));
        ((uint2*)h)[(size_t)nd1 * 16 + q] = p;
    }
}

// ---- 64-dim CSR gather over bf16 table (4/half main + staged remainder) ----
// out[n] = dis[n]*(sum_e dis[s]*ew*T[s] + dis[n]*T[n]) (+bias,relu)
template <bool RELU_BIAS, bool OUT_BF16>
__global__ __launch_bounds__(256) void k_gather64(const uint2* __restrict__ rec,
                                                  const int* __restrict__ rs,
                                                  const float* __restrict__ dis,
                                                  const unsigned* __restrict__ T,
                                                  const float* __restrict__ bias,
                                                  void* __restrict__ outv) {
    int wave = (blockIdx.x * 256 + threadIdx.x) >> 6;
    int lane = threadIdx.x & 63;
    int half = lane >> 5;
    int l    = lane & 31;         // col-pair index within row
    if (wave >= N_NODES) return;
    int n = wave;
    int begin = (n == 0) ? 0 : rs[n - 1];
    int end = rs[n];

    float ax0 = 0.f, ay0 = 0.f, ax1 = 0.f, ay1 = 0.f;
    float ax2 = 0.f, ay2 = 0.f, ax3 = 0.f, ay3 = 0.f;
    int k = begin + half;
    while (k + 6 < end) {                   // 4 records per half per iter
        uint2 r0 = rec[k];
        uint2 r1 = rec[k + 2];
        uint2 r2 = rec[k + 4];
        uint2 r3 = rec[k + 6];
        float d0 = dis[r0.x];
        float d1 = dis[r1.x];
        float d2 = dis[r2.x];
        float d3 = dis[r3.x];
        unsigned t0 = T[(size_t)r0.x * 32 + l];
        unsigned t1 = T[(size_t)r1.x * 32 + l];
        unsigned t2 = T[(size_t)r2.x * 32 + l];
        unsigned t3 = T[(size_t)r3.x * 32 + l];
        float n0 = d0 * __uint_as_float(r0.y);
        float n1 = d1 * __uint_as_float(r1.y);
        float n2 = d2 * __uint_as_float(r2.y);
        float n3 = d3 * __uint_as_float(r3.y);
        ax0 += bflo(t0) * n0; ay0 += bfhi(t0) * n0;
        ax1 += bflo(t1) * n1; ay1 += bfhi(t1) * n1;
        ax2 += bflo(t2) * n2; ay2 += bfhi(t2) * n2;
        ax3 += bflo(t3) * n3; ay3 += bfhi(t3) * n3;
        k += 8;
    }
    if (k + 2 < end) {                      // 2 records per half (mid stage)
        uint2 r0 = rec[k];
        uint2 r1 = rec[k + 2];
        float d0 = dis[r0.x];
        float d1 = dis[r1.x];
        unsigned t0 = T[(size_t)r0.x * 32 + l];
        unsigned t1 = T[(size_t)r1.x * 32 + l];
        float n0 = d0 * __uint_as_float(r0.y);
        float n1 = d1 * __uint_as_float(r1.y);
        ax0 += bflo(t0) * n0; ay0 += bfhi(t0) * n0;
        ax1 += bflo(t1) * n1; ay1 += bfhi(t1) * n1;
        k += 4;
    }
    if (k < end) {                          // final record for this half
        uint2 r = rec[k];
        float nn = dis[r.x] * __uint_as_float(r.y);
        unsigned t = T[(size_t)r.x * 32 + l];
        ax0 += bflo(t) * nn; ay0 += bfhi(t) * nn;
    }
    float ax = (ax0 + ax1) + (ax2 + ax3);
    float ay = (ay0 + ay1) + (ay2 + ay3);
    float di = dis[n];
    if (half == 0) {                        // self-loop (pre-factored form)
        unsigned t = T[(size_t)n * 32 + l];
        ax += bflo(t) * di; ay += bfhi(t) * di;
    }
    ax += __shfl_xor(ax, 32, 64);           // combine halves
    ay += __shfl_xor(ay, 32, 64);
    if (half == 0) {
        ax *= di; ay *= di;                 // wave-uniform dis[n] factor
        if (RELU_BIAS) {
            const float2* B2 = (const float2*)bias;
            float2 b = B2[l];
            ax += b.x; ay += b.y;
            ax = ax > 0.f ? ax : 0.f;
            ay = ay > 0.f ? ay : 0.f;
        }
        if (OUT_BF16) {
            ((unsigned*)outv)[(size_t)n * 32 + l] = bf16pack2(ax, ay);
        } else {
            ((float2*)outv)[(size_t)n * 32 + l] = make_float2(ax, ay);
        }
    }
}

// ---- fused: h2 = relu(agg2 @ W2 + b2); pool[batch] += h2 (run-length) ----
// k-outer / node-inner: w float4s read ONCE per k4, 8 live node accumulators.
__global__ __launch_bounds__(256) void k_gemm2_pool(const float* __restrict__ agg,
                                                    const float* __restrict__ W2,
                                                    const float* __restrict__ b2,
                                                    const int* __restrict__ batch,
                                                    float* __restrict__ pool) {
    __shared__ float Ws[HID * EMB];         // 32 KB
    __shared__ float as[NB2][HID];          // 16 KB (broadcast reads)
    __shared__ int   bs[NB2];
    int tid = threadIdx.x;
    const float4* W4 = (const float4*)W2;
    float4* Ws4 = (float4*)Ws;
    for (int i = tid; i < HID * EMB / 4; i += 256) Ws4[i] = W4[i];
    int base = blockIdx.x * NB2;
    const float4* A4 = (const float4*)agg;
    float4* as4 = (float4*)as;
    for (int i = tid; i < NB2 * HID / 4; i += 256) {
        int node = base + (i >> 4);
        as4[i] = (node < N_NODES) ? A4[(size_t)node * 16 + (i & 15)]
                                  : make_float4(0.f, 0.f, 0.f, 0.f);
    }
    if (tid < NB2) {
        int node = base + tid;
        bs[tid] = (node < N_NODES) ? batch[node] : -1;
    }
    __syncthreads();

    int c = tid & 31;             // column-quad id (4 cols)
    int s = tid >> 5;             // node slice 0..7 (8 contiguous nodes)
    int jc = c * 4;
    int nb = s * 8;
    float4 acc[8];
    #pragma unroll
    for (int i = 0; i < 8; ++i) acc[i] = make_float4(0.f, 0.f, 0.f, 0.f);
    #pragma unroll 4
    for (int k4 = 0; k4 < HID; k4 += 4) {
        float4 w0 = Ws4[(k4 + 0) * 32 + c];
        float4 w1 = Ws4[(k4 + 1) * 32 + c];
        float4 w2 = Ws4[(k4 + 2) * 32 + c];
        float4 w3 = Ws4[(k4 + 3) * 32 + c];
        #pragma unroll
        for (int i = 0; i < 8; ++i) {
            float4 av = *(const float4*)&as[nb + i][k4];
            fma4(acc[i], av.x, w0); fma4(acc[i], av.y, w1);
            fma4(acc[i], av.z, w2); fma4(acc[i], av.w, w3);
        }
    }
    // Epilogue: bias + relu + run-length pooled accumulate (batch sorted).
    float4 bq = *(const float4*)&b2[jc];
    float4 racc = make_float4(0.f, 0.f, 0.f, 0.f);
    int gcur = -1;
    #pragma unroll
    for (int i = 0; i < 8; ++i) {
        int g = bs[nb + i];
        if (g != gcur) {
            if (gcur >= 0) {
                float* p = &pool[(size_t)gcur * EMB + jc];
                atomicAdd(p + 0, racc.x); atomicAdd(p + 1, racc.y);
                atomicAdd(p + 2, racc.z); atomicAdd(p + 3, racc.w);
            }
            racc = make_float4(0.f, 0.f, 0.f, 0.f);
            gcur = g;
        }
        if (g < 0) continue;
        racc.x += fmaxf(acc[i].x + bq.x, 0.f);
        racc.y += fmaxf(acc[i].y + bq.y, 0.f);
        racc.z += fmaxf(acc[i].z + bq.z, 0.f);
        racc.w += fmaxf(acc[i].w + bq.w, 0.f);
    }
    if (gcur >= 0) {
        float* p = &pool[(size_t)gcur * EMB + jc];
        atomicAdd(p + 0, racc.x); atomicAdd(p + 1, racc.y);
        atomicAdd(p + 2, racc.z); atomicAdd(p + 3, racc.w);
    }
}

__global__ void k_divide(const float* __restrict__ pool, const int* __restrict__ gstart,
                         float* __restrict__ out) {
    int idx = blockIdx.x * blockDim.x + threadIdx.x;
    if (idx >= N_GRAPHS * EMB) return;
    int g = idx >> 7;
    float c = (float)(gstart[g + 1] - gstart[g]);
    out[idx] = pool[idx] / fmaxf(c, 1.0f);
}

extern "C" void kernel_launch(void* const* d_in, const int* in_sizes, int n_in,
                              void* d_out, int out_size, void* d_ws, size_t ws_size,
                              hipStream_t stream) {
    const float* x     = (const float*)d_in[0];
    const int*   eidx  = (const int*)d_in[1];     // [2, E]: src then dst
    const float* ew    = (const float*)d_in[2];
    const int*   batch = (const int*)d_in[3];
    const float* W1    = (const float*)d_in[4];
    const float* b1    = (const float*)d_in[5];
    const float* W2    = (const float*)d_in[6];
    const float* b2    = (const float*)d_in[7];
    float* out = (float*)d_out;

    const int* src = eidx;
    const int* dst = eidx + N_EDGES;

    float* ws     = (float*)d_ws;
    float* pool   = ws + OFF_POOL;
    int*   gstart = (int*)(ws + OFF_GST);
    int*   bbase  = (int*)(ws + OFF_BBASE);
    float* dis    = ws + OFF_DIS;
    int*   rs     = (int*)(ws + OFF_RS);
    int*   hcnt   = (int*)(ws + OFF_HCNT);
    uint2* rec    = (uint2*)(ws + OFF_REC);
    uint4* part   = (uint4*)(ws + OFF_PART);
    unsigned* h1  = (unsigned*)(ws + OFF_H1);   // bf16x2; overlays part (dead after P3)
    unsigned* h1p = (unsigned*)(ws + OFF_H1P);  // bf16x2
    float* agg2   = ws + OFF_AGG2;              // f32; overlays h1p (dead after gather1)

    // Only pool needs zeroing (everything else fully written).
    (void)hipMemsetAsync(pool, 0, (size_t)N_GRAPHS * EMB * sizeof(float), stream);

    // Bucket counting sort (no global atomics anywhere).
    k_p1<<<EB, 256, 0, stream>>>(dst, hcnt);
    k_kab<<<1, 256, 0, stream>>>(hcnt, bbase);
    k_kc<<<NBKT + GSB, 256, 0, stream>>>(hcnt, bbase, batch, gstart);
    k_p2<<<EB, 256, 0, stream>>>(src, dst, ew, hcnt, part);

    // Per-bucket CSR finalize + degree/dis, het-fused with layer-1 linear.
    k_p3_gemm1<<<NBKT + GB, 256, 0, stream>>>(part, bbase, rs, dis, rec, x, W1, h1p);

    // Layer 1 aggregate + bias + relu: bf16 table -> bf16 h1.
    k_gather64<true, true><<<N_NODES / 4, 256, 0, stream>>>(rec, rs, dis, h1p, b1, h1);

    // Layer 2 aggregate BEFORE the linear: bf16 h1 -> f32 agg2.
    k_gather64<false, false><<<N_NODES / 4, 256, 0, stream>>>(rec, rs, dis, h1, nullptr, agg2);

    // Fused layer-2 linear + relu + run-length pooled accumulate.
    k_gemm2_pool<<<(N_NODES + NB2 - 1) / NB2, 256, 0, stream>>>(agg2, W2, b2, batch, pool);

    k_divide<<<(N_GRAPHS * EMB + 255) / 256, 256, 0, stream>>>(pool, gstart, out);
}

// Round 16
// 230.064 us; speedup vs baseline: 1.9012x; 1.9012x over previous
//
#include <hip/hip_runtime.h>

// GCNEncoder round 16: round-15's finer buckets (128 nodes, NBKT=391) with the
// scan bottleneck fixed: bucket totals now computed by 391 PARALLEL blocks
// (k_btot) instead of one serial block (r15's k_kab was 220us, 1-block,
// uncoalesced). k_kab now only scans the 391-entry totals vector.
constexpr int N_NODES  = 50000;
constexpr int N_EDGES  = 800000;
constexpr int N_GRAPHS = 256;
constexpr int IN_DIM   = 128;
constexpr int HID      = 64;
constexpr int EMB      = 128;
constexpr int NBKT     = 391;                       // buckets: dst>>7 (128 nodes)
constexpr int EB       = (N_EDGES + 1023) / 1024;   // 782 edge blocks
constexpr int GB       = (N_NODES + 31) / 32;       // 1563 gemm1 blocks (32 nodes)
constexpr int GSB      = (N_NODES + 255) / 256;     // 196 gstart blocks
constexpr int NB2      = 64;                        // nodes per gemm2_pool block

// Workspace layout in 4-byte units (~33.8 MB; ws is 268 MB).
constexpr size_t OFF_POOL  = 0;                                 // f32 [256*128]
constexpr size_t OFF_GST   = 32768;                             // i32 [257]
constexpr size_t OFF_BBASE = 33026;                             // i32 [392]
constexpr size_t OFF_BTOT  = 33418;                             // i32 [391]
constexpr size_t OFF_DIS   = 33812;                             // f32 [50000]
constexpr size_t OFF_RS    = 83812;                             // i32 [50000]
constexpr size_t OFF_HCNT  = 133812;                            // i32 [782*391]
constexpr size_t OFF_REC   = 439576;                            // uint2 [800000] (8B-aligned)
constexpr size_t OFF_PART  = OFF_REC + 2 * (size_t)N_EDGES;     // uint4 [800000] (16B-aligned)
constexpr size_t OFF_H1    = OFF_PART;  // bf16x2 [50000*32]; overlays part (dead after P3)
constexpr size_t OFF_H1P   = OFF_PART + 4 * (size_t)N_EDGES;    // bf16x2 [50000*32]
constexpr size_t OFF_AGG2  = OFF_H1P;   // f32 [50000*64]; overlays h1p (dead after gather1)

// bf16 helpers: pack with round-to-nearest-even; unpack via shift.
__device__ inline unsigned bf16r(float f) {
    unsigned u = __float_as_uint(f);
    return (u + 0x7fffu + ((u >> 16) & 1u)) >> 16;
}
__device__ inline unsigned bf16pack2(float lo, float hi) {
    return bf16r(lo) | (bf16r(hi) << 16);
}
__device__ inline float bflo(unsigned v) { return __uint_as_float(v << 16); }
__device__ inline float bfhi(unsigned v) { return __uint_as_float(v & 0xffff0000u); }

__device__ inline void fma4(float4& acc, float s, const float4& v) {
    acc.x += s * v.x; acc.y += s * v.y; acc.z += s * v.z; acc.w += s * v.w;
}

// ---- P1: per-block bucket histogram (LDS atomics only) ----
__global__ __launch_bounds__(256) void k_p1(const int* __restrict__ dst,
                                            int* __restrict__ hcnt) {
    __shared__ int lh[NBKT];
    int tid = threadIdx.x;
    for (int i = tid; i < NBKT; i += 256) lh[i] = 0;
    __syncthreads();
    int base = blockIdx.x * 1024;
    #pragma unroll
    for (int j = 0; j < 4; ++j) {
        int e = base + j * 256 + tid;
        if (e < N_EDGES) atomicAdd(&lh[dst[e] >> 7], 1);
    }
    __syncthreads();
    for (int i = tid; i < NBKT; i += 256) hcnt[blockIdx.x * NBKT + i] = lh[i];
}

// ---- BTOT: bucket b total = sum over 782 rows (one block per bucket) ----
__global__ __launch_bounds__(256) void k_btot(const int* __restrict__ hcnt,
                                              int* __restrict__ btot) {
    __shared__ int red[256];
    int b = blockIdx.x;
    int t = threadIdx.x;
    int v = 0;
    for (int i = t; i < EB; i += 256) v += hcnt[i * NBKT + b];
    red[t] = v;
    __syncthreads();
    for (int off = 128; off > 0; off >>= 1) {
        if (t < off) red[t] += red[t + off];
        __syncthreads();
    }
    if (t == 0) btot[b] = red[0];
}

// ---- KAB: exclusive scan of btot[391] -> bbase[392] (one block, tiny) ----
__global__ __launch_bounds__(256) void k_kab(const int* __restrict__ btot,
                                             int* __restrict__ bbase) {
    __shared__ int tile[512];
    int t = threadIdx.x;
    int v0 = btot[t < NBKT ? t : 0];
    if (t >= NBKT) v0 = 0;
    int v1 = (t + 256 < NBKT) ? btot[t + 256] : 0;
    tile[t] = v0;
    tile[256 + t] = v1;
    __syncthreads();
    for (int off = 1; off < 256; off <<= 1) {
        int a0 = (t >= off) ? tile[t - off] : 0;
        int a1 = (t >= off) ? tile[256 + t - off] : 0;
        __syncthreads();
        tile[t] += a0;
        tile[256 + t] += a1;
        __syncthreads();
    }
    int h0 = tile[255];                       // first-half inclusive total
    tile[256 + t] += h0;
    if (t < NBKT) bbase[t] = tile[t] - v0;    // exclusive
    if (t + 256 < NBKT) bbase[256 + t] = tile[256 + t] - v1;
    if (t + 256 == NBKT - 1) bbase[NBKT] = tile[256 + t];   // total = N_EDGES
}

// ---- KC: per-bucket column scan of hcnt in place (+ gstart role) ----
__global__ __launch_bounds__(256) void k_kc(int* __restrict__ hcnt,
                                            const int* __restrict__ bbase,
                                            const int* __restrict__ batch,
                                            int* __restrict__ gstart) {
    __shared__ int tile[256];
    __shared__ int carry;
    int t = threadIdx.x;
    if (blockIdx.x < NBKT) {
        int b = blockIdx.x;
        if (t == 0) carry = bbase[b];
        __syncthreads();
        for (int i0 = 0; i0 < EB; i0 += 256) {
            int i = i0 + t;
            int v = (i < EB) ? hcnt[i * NBKT + b] : 0;
            tile[t] = v;
            __syncthreads();
            for (int off = 1; off < 256; off <<= 1) {
                int a = (t >= off) ? tile[t - off] : 0;
                __syncthreads();
                tile[t] += a;
                __syncthreads();
            }
            int incl = tile[t];
            if (i < EB) hcnt[i * NBKT + b] = carry + incl - v;   // exclusive + carry
            __syncthreads();
            if (t == 255) carry += incl;
            __syncthreads();
        }
        return;
    }
    // ---- gstart role: sorted-batch boundary detection ----
    int i = (blockIdx.x - NBKT) * 256 + t;
    if (i >= N_NODES) return;
    int g = batch[i];
    if (i == 0) {
        for (int gg = 0; gg <= g; ++gg) gstart[gg] = 0;
    } else {
        int gp = batch[i - 1];
        for (int gg = gp + 1; gg <= g; ++gg) gstart[gg] = i;
    }
    if (i == N_NODES - 1) {
        for (int gg = g + 1; gg <= N_GRAPHS; ++gg) gstart[gg] = N_NODES;
    }
}

// ---- P2: partition edges into buckets (LDS cursors, no global atomics) ----
__global__ __launch_bounds__(256) void k_p2(const int* __restrict__ src,
                                            const int* __restrict__ dst,
                                            const float* __restrict__ ew,
                                            const int* __restrict__ hcnt,
                                            uint4* __restrict__ part) {
    __shared__ int lb[NBKT];
    __shared__ int lc[NBKT];
    int tid = threadIdx.x;
    for (int i = tid; i < NBKT; i += 256) {
        lb[i] = hcnt[blockIdx.x * NBKT + i];
        lc[i] = 0;
    }
    __syncthreads();
    int base = blockIdx.x * 1024;
    #pragma unroll
    for (int j = 0; j < 4; ++j) {
        int e = base + j * 256 + tid;
        if (e < N_EDGES) {
            int d = dst[e];
            int b = d >> 7;
            int r = atomicAdd(&lc[b], 1);
            part[lb[b] + r] = make_uint4((unsigned)src[e], (unsigned)d,
                                         __float_as_uint(ew[e]), 0u);
        }
    }
}

// ---- P3 (+gemm1 het-fused): per-bucket CSR finalize + degree + dis ----
// blocks [0,NBKT): bucket b = 128 contiguous nodes; ~2040 records/block.
// blocks [NBKT,NBKT+GB): h1p(bf16) = x @ W1 (32 nodes/block).
__global__ __launch_bounds__(256) void k_p3_gemm1(const uint4* __restrict__ part,
                                                  const int* __restrict__ bbase,
                                                  int* __restrict__ rs,
                                                  float* __restrict__ dis,
                                                  uint2* __restrict__ rec,
                                                  const float* __restrict__ x,
                                                  const float* __restrict__ W1,
                                                  unsigned* __restrict__ h) {
    __shared__ float Ws[IN_DIM * HID];      // 32 KB (gemm role)
    __shared__ float xs[32][IN_DIM + 4];    // 16.5 KB, stride 132 -> conflict-free
    __shared__ int   cnt[128];
    __shared__ float dgw[128];
    __shared__ int   scn[128];
    __shared__ int   cur[128];
    int tid = threadIdx.x;
    if (blockIdx.x < NBKT) {
        int b = blockIdx.x;
        int base_node = b << 7;
        int ebeg = bbase[b], eend = bbase[b + 1];
        if (tid < 128) { cnt[tid] = 0; dgw[tid] = 0.f; }
        __syncthreads();
        for (int e = ebeg + tid; e < eend; e += 256) {
            uint4 r = part[e];
            int ld = (int)r.y & 127;
            atomicAdd(&cnt[ld], 1);
            atomicAdd(&dgw[ld], __uint_as_float(r.z));
        }
        __syncthreads();
        if (tid < 128) scn[tid] = cnt[tid];
        __syncthreads();
        for (int off = 1; off < 128; off <<= 1) {
            int a = (tid >= off && tid < 128) ? scn[tid - off] : 0;
            __syncthreads();
            if (tid < 128) scn[tid] += a;
            __syncthreads();
        }
        if (tid < 128) {
            int node = base_node + tid;
            if (node < N_NODES) {
                rs[node] = ebeg + scn[tid];             // end pointer
                dis[node] = rsqrtf(dgw[tid] + 1.0f);    // + self-loop weight 1
            }
            cur[tid] = ebeg + scn[tid] - cnt[tid];      // row start cursor
        }
        __syncthreads();
        for (int e = ebeg + tid; e < eend; e += 256) {
            uint4 r = part[e];
            int ld = (int)r.y & 127;
            int pos = atomicAdd(&cur[ld], 1);
            rec[pos] = make_uint2(r.x, r.z);            // (src, ew_bits)
        }
        return;
    }
    // ---- gemm1 role: 32 nodes/block, thread = 2 nodes x 4 cols ----
    int bid = blockIdx.x - NBKT;
    const float4* W4 = (const float4*)W1;
    float4* Ws4 = (float4*)Ws;
    for (int i = tid; i < IN_DIM * HID / 4; i += 256) Ws4[i] = W4[i];
    int base = bid * 32;
    const float4* X4 = (const float4*)x;
    for (int i = tid; i < 32 * 32; i += 256) {           // 32 rows x 32 float4
        int ln = i >> 5, kq = i & 31;
        int node = base + ln;
        float4 v = (node < N_NODES) ? X4[(size_t)node * 32 + kq]
                                    : make_float4(0.f, 0.f, 0.f, 0.f);
        *(float4*)&xs[ln][kq * 4] = v;
    }
    __syncthreads();
    int np = tid >> 4;            // node pair 0..15
    int q  = tid & 15;            // col quad 0..15
    int n0 = np * 2, n1 = n0 + 1;
    float4 a0 = make_float4(0.f, 0.f, 0.f, 0.f);
    float4 a1 = a0;
    #pragma unroll 4
    for (int k4 = 0; k4 < IN_DIM; k4 += 4) {
        float4 xv0 = *(const float4*)&xs[n0][k4];
        float4 xv1 = *(const float4*)&xs[n1][k4];
        float4 w0 = Ws4[(k4 + 0) * 16 + q];
        float4 w1 = Ws4[(k4 + 1) * 16 + q];
        float4 w2 = Ws4[(k4 + 2) * 16 + q];
        float4 w3 = Ws4[(k4 + 3) * 16 + q];
        fma4(a0, xv0.x, w0); fma4(a0, xv0.y, w1); fma4(a0, xv0.z, w2); fma4(a0, xv0.w, w3);
        fma4(a1, xv1.x, w0); fma4(a1, xv1.y, w1); fma4(a1, xv1.z, w2); fma4(a1, xv1.w, w3);
    }
    int nd0 = base + n0, nd1 = base + n1;
    if (nd0 < N_NODES) {
        uint2 p = make_uint2(bf16pack2(a0.x, a0.y), bf16pack2(a0.z, a0.w));
        ((uint2*)h)[(size_t)nd0 * 16 + q] = p;
    }
    if (nd1 < N_NODES) {
        uint2 p = make_uint2(bf16pack2(a1.x, a1.y), bf16pack2(a1.z, a1.w));
        ((uint2*)h)[(size_t)nd1 * 16 + q] = p;
    }
}

// ---- 64-dim CSR gather over bf16 table (4/half main + staged remainder) ----
// out[n] = dis[n]*(sum_e dis[s]*ew*T[s] + dis[n]*T[n]) (+bias,relu)
template <bool RELU_BIAS, bool OUT_BF16>
__global__ __launch_bounds__(256) void k_gather64(const uint2* __restrict__ rec,
                                                  const int* __restrict__ rs,
                                                  const float* __restrict__ dis,
                                                  const unsigned* __restrict__ T,
                                                  const float* __restrict__ bias,
                                                  void* __restrict__ outv) {
    int wave = (blockIdx.x * 256 + threadIdx.x) >> 6;
    int lane = threadIdx.x & 63;
    int half = lane >> 5;
    int l    = lane & 31;         // col-pair index within row
    if (wave >= N_NODES) return;
    int n = wave;
    int begin = (n == 0) ? 0 : rs[n - 1];
    int end = rs[n];

    float ax0 = 0.f, ay0 = 0.f, ax1 = 0.f, ay1 = 0.f;
    float ax2 = 0.f, ay2 = 0.f, ax3 = 0.f, ay3 = 0.f;
    int k = begin + half;
    while (k + 6 < end) {                   // 4 records per half per iter
        uint2 r0 = rec[k];
        uint2 r1 = rec[k + 2];
        uint2 r2 = rec[k + 4];
        uint2 r3 = rec[k + 6];
        float d0 = dis[r0.x];
        float d1 = dis[r1.x];
        float d2 = dis[r2.x];
        float d3 = dis[r3.x];
        unsigned t0 = T[(size_t)r0.x * 32 + l];
        unsigned t1 = T[(size_t)r1.x * 32 + l];
        unsigned t2 = T[(size_t)r2.x * 32 + l];
        unsigned t3 = T[(size_t)r3.x * 32 + l];
        float n0 = d0 * __uint_as_float(r0.y);
        float n1 = d1 * __uint_as_float(r1.y);
        float n2 = d2 * __uint_as_float(r2.y);
        float n3 = d3 * __uint_as_float(r3.y);
        ax0 += bflo(t0) * n0; ay0 += bfhi(t0) * n0;
        ax1 += bflo(t1) * n1; ay1 += bfhi(t1) * n1;
        ax2 += bflo(t2) * n2; ay2 += bfhi(t2) * n2;
        ax3 += bflo(t3) * n3; ay3 += bfhi(t3) * n3;
        k += 8;
    }
    if (k + 2 < end) {                      // 2 records per half (mid stage)
        uint2 r0 = rec[k];
        uint2 r1 = rec[k + 2];
        float d0 = dis[r0.x];
        float d1 = dis[r1.x];
        unsigned t0 = T[(size_t)r0.x * 32 + l];
        unsigned t1 = T[(size_t)r1.x * 32 + l];
        float n0 = d0 * __uint_as_float(r0.y);
        float n1 = d1 * __uint_as_float(r1.y);
        ax0 += bflo(t0) * n0; ay0 += bfhi(t0) * n0;
        ax1 += bflo(t1) * n1; ay1 += bfhi(t1) * n1;
        k += 4;
    }
    if (k < end) {                          // final record for this half
        uint2 r = rec[k];
        float nn = dis[r.x] * __uint_as_float(r.y);
        unsigned t = T[(size_t)r.x * 32 + l];
        ax0 += bflo(t) * nn; ay0 += bfhi(t) * nn;
    }
    float ax = (ax0 + ax1) + (ax2 + ax3);
    float ay = (ay0 + ay1) + (ay2 + ay3);
    float di = dis[n];
    if (half == 0) {                        // self-loop (pre-factored form)
        unsigned t = T[(size_t)n * 32 + l];
        ax += bflo(t) * di; ay += bfhi(t) * di;
    }
    ax += __shfl_xor(ax, 32, 64);           // combine halves
    ay += __shfl_xor(ay, 32, 64);
    if (half == 0) {
        ax *= di; ay *= di;                 // wave-uniform dis[n] factor
        if (RELU_BIAS) {
            const float2* B2 = (const float2*)bias;
            float2 b = B2[l];
            ax += b.x; ay += b.y;
            ax = ax > 0.f ? ax : 0.f;
            ay = ay > 0.f ? ay : 0.f;
        }
        if (OUT_BF16) {
            ((unsigned*)outv)[(size_t)n * 32 + l] = bf16pack2(ax, ay);
        } else {
            ((float2*)outv)[(size_t)n * 32 + l] = make_float2(ax, ay);
        }
    }
}

// ---- fused: h2 = relu(agg2 @ W2 + b2); pool[batch] += h2 (run-length) ----
// k-outer / node-inner: w float4s read ONCE per k4, 8 live node accumulators.
__global__ __launch_bounds__(256) void k_gemm2_pool(const float* __restrict__ agg,
                                                    const float* __restrict__ W2,
                                                    const float* __restrict__ b2,
                                                    const int* __restrict__ batch,
                                                    float* __restrict__ pool) {
    __shared__ float Ws[HID * EMB];         // 32 KB
    __shared__ float as[NB2][HID];          // 16 KB (broadcast reads)
    __shared__ int   bs[NB2];
    int tid = threadIdx.x;
    const float4* W4 = (const float4*)W2;
    float4* Ws4 = (float4*)Ws;
    for (int i = tid; i < HID * EMB / 4; i += 256) Ws4[i] = W4[i];
    int base = blockIdx.x * NB2;
    const float4* A4 = (const float4*)agg;
    float4* as4 = (float4*)as;
    for (int i = tid; i < NB2 * HID / 4; i += 256) {
        int node = base + (i >> 4);
        as4[i] = (node < N_NODES) ? A4[(size_t)node * 16 + (i & 15)]
                                  : make_float4(0.f, 0.f, 0.f, 0.f);
    }
    if (tid < NB2) {
        int node = base + tid;
        bs[tid] = (node < N_NODES) ? batch[node] : -1;
    }
    __syncthreads();

    int c = tid & 31;             // column-quad id (4 cols)
    int s = tid >> 5;             // node slice 0..7 (8 contiguous nodes)
    int jc = c * 4;
    int nb = s * 8;
    float4 acc[8];
    #pragma unroll
    for (int i = 0; i < 8; ++i) acc[i] = make_float4(0.f, 0.f, 0.f, 0.f);
    #pragma unroll 4
    for (int k4 = 0; k4 < HID; k4 += 4) {
        float4 w0 = Ws4[(k4 + 0) * 32 + c];
        float4 w1 = Ws4[(k4 + 1) * 32 + c];
        float4 w2 = Ws4[(k4 + 2) * 32 + c];
        float4 w3 = Ws4[(k4 + 3) * 32 + c];
        #pragma unroll
        for (int i = 0; i < 8; ++i) {
            float4 av = *(const float4*)&as[nb + i][k4];
            fma4(acc[i], av.x, w0); fma4(acc[i], av.y, w1);
            fma4(acc[i], av.z, w2); fma4(acc[i], av.w, w3);
        }
    }
    // Epilogue: bias + relu + run-length pooled accumulate (batch sorted).
    float4 bq = *(const float4*)&b2[jc];
    float4 racc = make_float4(0.f, 0.f, 0.f, 0.f);
    int gcur = -1;
    #pragma unroll
    for (int i = 0; i < 8; ++i) {
        int g = bs[nb + i];
        if (g != gcur) {
            if (gcur >= 0) {
                float* p = &pool[(size_t)gcur * EMB + jc];
                atomicAdd(p + 0, racc.x); atomicAdd(p + 1, racc.y);
                atomicAdd(p + 2, racc.z); atomicAdd(p + 3, racc.w);
            }
            racc = make_float4(0.f, 0.f, 0.f, 0.f);
            gcur = g;
        }
        if (g < 0) continue;
        racc.x += fmaxf(acc[i].x + bq.x, 0.f);
        racc.y += fmaxf(acc[i].y + bq.y, 0.f);
        racc.z += fmaxf(acc[i].z + bq.z, 0.f);
        racc.w += fmaxf(acc[i].w + bq.w, 0.f);
    }
    if (gcur >= 0) {
        float* p = &pool[(size_t)gcur * EMB + jc];
        atomicAdd(p + 0, racc.x); atomicAdd(p + 1, racc.y);
        atomicAdd(p + 2, racc.z); atomicAdd(p + 3, racc.w);
    }
}

__global__ void k_divide(const float* __restrict__ pool, const int* __restrict__ gstart,
                         float* __restrict__ out) {
    int idx = blockIdx.x * blockDim.x + threadIdx.x;
    if (idx >= N_GRAPHS * EMB) return;
    int g = idx >> 7;
    float c = (float)(gstart[g + 1] - gstart[g]);
    out[idx] = pool[idx] / fmaxf(c, 1.0f);
}

extern "C" void kernel_launch(void* const* d_in, const int* in_sizes, int n_in,
                              void* d_out, int out_size, void* d_ws, size_t ws_size,
                              hipStream_t stream) {
    const float* x     = (const float*)d_in[0];
    const int*   eidx  = (const int*)d_in[1];     // [2, E]: src then dst
    const float* ew    = (const float*)d_in[2];
    const int*   batch = (const int*)d_in[3];
    const float* W1    = (const float*)d_in[4];
    const float* b1    = (const float*)d_in[5];
    const float* W2    = (const float*)d_in[6];
    const float* b2    = (const float*)d_in[7];
    float* out = (float*)d_out;

    const int* src = eidx;
    const int* dst = eidx + N_EDGES;

    float* ws     = (float*)d_ws;
    float* pool   = ws + OFF_POOL;
    int*   gstart = (int*)(ws + OFF_GST);
    int*   bbase  = (int*)(ws + OFF_BBASE);
    int*   btot   = (int*)(ws + OFF_BTOT);
    float* dis    = ws + OFF_DIS;
    int*   rs     = (int*)(ws + OFF_RS);
    int*   hcnt   = (int*)(ws + OFF_HCNT);
    uint2* rec    = (uint2*)(ws + OFF_REC);
    uint4* part   = (uint4*)(ws + OFF_PART);
    unsigned* h1  = (unsigned*)(ws + OFF_H1);   // bf16x2; overlays part (dead after P3)
    unsigned* h1p = (unsigned*)(ws + OFF_H1P);  // bf16x2
    float* agg2   = ws + OFF_AGG2;              // f32; overlays h1p (dead after gather1)

    // Only pool needs zeroing (everything else fully written).
    (void)hipMemsetAsync(pool, 0, (size_t)N_GRAPHS * EMB * sizeof(float), stream);

    // Bucket counting sort (no global atomics anywhere).
    k_p1<<<EB, 256, 0, stream>>>(dst, hcnt);
    k_btot<<<NBKT, 256, 0, stream>>>(hcnt, btot);
    k_kab<<<1, 256, 0, stream>>>(btot, bbase);
    k_kc<<<NBKT + GSB, 256, 0, stream>>>(hcnt, bbase, batch, gstart);
    k_p2<<<EB, 256, 0, stream>>>(src, dst, ew, hcnt, part);

    // Per-bucket CSR finalize + degree/dis, het-fused with layer-1 linear.
    k_p3_gemm1<<<NBKT + GB, 256, 0, stream>>>(part, bbase, rs, dis, rec, x, W1, h1p);

    // Layer 1 aggregate + bias + relu: bf16 table -> bf16 h1.
    k_gather64<true, true><<<N_NODES / 4, 256, 0, stream>>>(rec, rs, dis, h1p, b1, h1);

    // Layer 2 aggregate BEFORE the linear: bf16 h1 -> f32 agg2.
    k_gather64<false, false><<<N_NODES / 4, 256, 0, stream>>>(rec, rs, dis, h1, nullptr, agg2);

    // Fused layer-2 linear + relu + run-length pooled accumulate.
    k_gemm2_pool<<<(N_NODES + NB2 - 1) / NB2, 256, 0, stream>>>(agg2, W2, b2, batch, pool);

    k_divide<<<(N_GRAPHS * EMB + 255) / 256, 256, 0, stream>>>(pool, gstart, out);
}